// Round 1
// baseline (81.635 us; speedup 1.0000x reference)
//
#include <hip/hip_runtime.h>

// Problem constants (from reference): B=64, C=1024, H=W=32 -> HW=1024.
#define NB 64
#define NC 1024
#define NHW 1024

__device__ inline float wave_reduce_max(float v) {
    #pragma unroll
    for (int off = 32; off; off >>= 1) v = fmaxf(v, __shfl_xor(v, off));
    return v;
}
__device__ inline float wave_reduce_sum(float v) {
    #pragma unroll
    for (int off = 32; off; off >>= 1) v += __shfl_xor(v, off);
    return v;
}

// K1: scores[b*NHW + hw] = sum_c x[(b*NC + c)*NHW + hw] * w[c] + bias
// grid = NB * (NHW/256) = 256 blocks, block = 256 threads, thread-per-(b,hw)
__global__ __launch_bounds__(256) void scores_kernel(
        const float* __restrict__ x, const float* __restrict__ w,
        const float* __restrict__ bias, float* __restrict__ scores) {
    const int b  = blockIdx.x >> 2;                 // 4 blocks per batch
    const int hw = ((blockIdx.x & 3) << 8) + threadIdx.x;
    const float* xb = x + ((size_t)b * NC) * NHW + hw;
    float acc = 0.0f;
    #pragma unroll 16
    for (int c = 0; c < NC; ++c) {
        acc += xb[(size_t)c * NHW] * w[c];          // w[c] lane-uniform -> s_load
    }
    scores[b * NHW + hw] = acc + bias[0];
}

// K2: in-place softmax over the NHW=1024 scores of one batch.
// grid = NB, block = 256 threads (each owns one float4 of the row).
__global__ __launch_bounds__(256) void softmax_kernel(float* __restrict__ scores) {
    __shared__ float redm[4];
    __shared__ float reds[4];
    const int tid  = threadIdx.x;
    const int wave = tid >> 6, lane = tid & 63;
    float4* row = reinterpret_cast<float4*>(scores + blockIdx.x * NHW);
    float4 v = row[tid];

    float m = fmaxf(fmaxf(v.x, v.y), fmaxf(v.z, v.w));
    m = wave_reduce_max(m);
    if (lane == 0) redm[wave] = m;
    __syncthreads();
    m = fmaxf(fmaxf(redm[0], redm[1]), fmaxf(redm[2], redm[3]));

    float4 e;
    e.x = __expf(v.x - m); e.y = __expf(v.y - m);
    e.z = __expf(v.z - m); e.w = __expf(v.w - m);
    float s = e.x + e.y + e.z + e.w;
    s = wave_reduce_sum(s);
    if (lane == 0) reds[wave] = s;
    __syncthreads();
    const float inv = 1.0f / (reds[0] + reds[1] + reds[2] + reds[3]);

    e.x *= inv; e.y *= inv; e.z *= inv; e.w *= inv;
    row[tid] = e;   // each thread rewrites only its own float4 -> no hazard
}

// K3: out[b*NC + c] = sum_hw x[(b*NC + c)*NHW + hw] * attn[b*NHW + hw]
// One wave per output; block = 256 threads = 4 outputs; grid = NB*NC/4 = 16384.
__global__ __launch_bounds__(256) void pool_kernel(
        const float* __restrict__ x, const float* __restrict__ attn,
        float* __restrict__ out) {
    const int wave = threadIdx.x >> 6;
    const int lane = threadIdx.x & 63;
    const int out_idx = (blockIdx.x << 2) + wave;   // = b*NC + c
    const int b = out_idx >> 10;                    // NC = 1024
    const float4* xr = reinterpret_cast<const float4*>(x + (size_t)out_idx * NHW);
    const float4* ar = reinterpret_cast<const float4*>(attn + b * NHW);

    float acc = 0.0f;
    #pragma unroll
    for (int i = 0; i < 4; ++i) {                   // 4 * 64 lanes * 4 floats = 1024
        const float4 xv = xr[(i << 6) + lane];
        const float4 av = ar[(i << 6) + lane];
        acc += xv.x * av.x + xv.y * av.y + xv.z * av.z + xv.w * av.w;
    }
    acc = wave_reduce_sum(acc);
    if (lane == 0) out[out_idx] = acc;
}

extern "C" void kernel_launch(void* const* d_in, const int* in_sizes, int n_in,
                              void* d_out, int out_size, void* d_ws, size_t ws_size,
                              hipStream_t stream) {
    const float* x    = (const float*)d_in[0];
    const float* w    = (const float*)d_in[1];
    const float* bias = (const float*)d_in[2];
    float* out    = (float*)d_out;
    float* scores = (float*)d_ws;                   // NB*NHW floats = 256 KB

    scores_kernel <<<NB * (NHW / 256), 256, 0, stream>>>(x, w, bias, scores);
    softmax_kernel<<<NB,               256, 0, stream>>>(scores);
    pool_kernel   <<<(NB * NC) / 4,    256, 0, stream>>>(x, scores, out);
}